// Round 1
// baseline (60.676 us; speedup 1.0000x reference)
//
#include <hip/hip_runtime.h>

// GlobalConvolutionalLayer: out[n,c,m] = 0.5*xi_eff[c]*dx * sum_l d[n,l]*exp(-|x_l-x_m|*xi_eff[c])
// Separable exponential kernel on a sorted uniform grid:
//   out[m] = scale * ( e^{-x_m k} * A_m + e^{+x_m k} * B_m )
//   A_m = sum_{l<=m} d[l] e^{+x_l k},  B_m = sum_{l>m} d[l] e^{-x_l k}
// xi_eff = 1/sigmoid(xi) = 1 + exp(-xi) in (1.37, 2]; exp(x*k) <= e^2, no overflow.
//
// v2: two-phase decoupled scan. Old kernel used only 32 blocks (12.5% of CUs,
// 1 wave/SIMD) with a 16-step serial per-thread chain -> latency-bound ~19us.
// Split each (n,c) scan into SS=16 segments -> 512 blocks (2/CU), phase 1
// computes segment totals into d_ws, phase 2 applies offsets + block scan.

#define GG 4096
#define CC 8
#define NN 4
#define SS 16               // segments per (n,c) scan
#define SEG (GG / SS)       // 256 elements per segment = 1 per thread
#define BLOCK 256
#define NCOMBO (NN * CC)    // 32
#define NBLK (NCOMBO * SS)  // 512 blocks

__global__ __launch_bounds__(BLOCK) void gconv_part(const float* __restrict__ density,
                                                    const float* __restrict__ xi,
                                                    const float* __restrict__ grid,
                                                    float* __restrict__ ws) {
    const int bid   = blockIdx.x;
    const int seg   = bid & (SS - 1);
    const int combo = bid >> 4;          // log2(SS) = 4
    const int c     = combo & (CC - 1);
    const int n     = combo >> 3;        // log2(CC) = 3
    const int tid   = threadIdx.x;
    const int g     = seg * SEG + tid;

    const float k  = 1.0f + expf(-xi[c]);        // xi_eff = 1/sigmoid(xi)
    const float x  = grid[g];
    const float d  = density[n * GG + g];
    const float xk = x * k;
    float sA = d * expf(xk);
    float sB = d * expf(-xk);

    // 64-lane butterfly reduce
#pragma unroll
    for (int off = 32; off > 0; off >>= 1) {
        sA += __shfl_xor(sA, off, 64);
        sB += __shfl_xor(sB, off, 64);
    }
    __shared__ float wA[BLOCK / 64], wB[BLOCK / 64];
    const int wave = tid >> 6;
    if ((tid & 63) == 0) { wA[wave] = sA; wB[wave] = sB; }
    __syncthreads();
    if (tid == 0) {
        ws[bid]        = wA[0] + wA[1] + wA[2] + wA[3];  // TA[combo][seg]
        ws[NBLK + bid] = wB[0] + wB[1] + wB[2] + wB[3];  // TB[combo][seg]
    }
}

__global__ __launch_bounds__(BLOCK) void gconv_out(const float* __restrict__ density,
                                                   const float* __restrict__ xi,
                                                   const float* __restrict__ grid,
                                                   const float* __restrict__ ws,
                                                   float* __restrict__ out) {
    const int bid   = blockIdx.x;
    const int seg   = bid & (SS - 1);
    const int combo = bid >> 4;
    const int c     = combo & (CC - 1);
    const int n     = combo >> 3;
    const int tid   = threadIdx.x;
    const int lane  = tid & 63;
    const int wave  = tid >> 6;
    const int g     = seg * SEG + tid;

    const float k  = 1.0f + expf(-xi[c]);
    const float dx = grid[1] - grid[0];          // uniform spacing = 1/G
    const float x  = grid[g];
    const float d  = density[n * GG + g];
    const float xk = x * k;
    const float ea = expf(xk);
    const float eb = expf(-xk);
    const float a  = d * ea;
    const float b  = d * eb;

    // cross-segment offsets: uniform per block, L2-hit scalar loads
    const float* TA = ws + combo * SS;
    const float* TB = ws + NBLK + combo * SS;
    float offA = 0.0f, offB = 0.0f;
#pragma unroll
    for (int s = 0; s < SS; ++s) {
        const float ta = TA[s];
        const float tb = TB[s];
        if (s < seg) offA += ta;   // segments strictly before
        if (s > seg) offB += tb;   // segments strictly after
    }

    // wave-level inclusive prefix of a, inclusive suffix of b
    float pa = a, sb = b;
#pragma unroll
    for (int off = 1; off < 64; off <<= 1) {
        const float tA = __shfl_up(pa, off, 64);
        if (lane >= off) pa += tA;
        const float tB = __shfl_down(sb, off, 64);
        if (lane + off < 64) sb += tB;
    }

    // cross-wave combine (4 waves)
    __shared__ float wTA[BLOCK / 64], wTB[BLOCK / 64];
    if (lane == 63) wTA[wave] = pa;   // wave total of a
    if (lane == 0)  wTB[wave] = sb;   // wave total of b
    __syncthreads();
    float wOffA = 0.0f, wOffB = 0.0f;
#pragma unroll
    for (int w = 0; w < BLOCK / 64; ++w) {
        if (w < wave) wOffA += wTA[w];
        if (w > wave) wOffB += wTB[w];
    }

    const float A = offA + wOffA + pa;         // sum_{l<=g} d[l] e^{+x_l k}
    const float B = offB + wOffB + (sb - b);   // sum_{l>g}  d[l] e^{-x_l k}
    const float scale = 0.5f * k * dx;
    out[(n * CC + c) * GG + g] = scale * (eb * A + ea * B);
}

extern "C" void kernel_launch(void* const* d_in, const int* in_sizes, int n_in,
                              void* d_out, int out_size, void* d_ws, size_t ws_size,
                              hipStream_t stream) {
    const float* density = (const float*)d_in[0];  // (N,1,G) fp32
    const float* xi      = (const float*)d_in[1];  // (C,)    fp32
    const float* grid    = (const float*)d_in[2];  // (G,)    fp32
    float* out           = (float*)d_out;          // (N,C,G) fp32
    float* ws            = (float*)d_ws;           // 2*NBLK floats of partials

    gconv_part<<<NBLK, BLOCK, 0, stream>>>(density, xi, grid, ws);
    gconv_out<<<NBLK, BLOCK, 0, stream>>>(density, xi, grid, ws, out);
}